// Round 13
// baseline (92.870 us; speedup 1.0000x reference)
//
#include <hip/hip_runtime.h>

#define SC 20
#define HDIM 10
#define VOCAB 256
#define SENT VOCAB       // sentinel zero ctab row
#define CROWH 60         // ctab row stride in halves (120 B: 8B-aligned slices, 16 bank-groups)
#define XROW 32          // X row stride in halves (64 B): 12 x | 10 h | bias | pad(9)=0
#define WAVES 8

typedef _Float16 f16;
typedef __attribute__((ext_vector_type(2))) _Float16 f16x2;
typedef __attribute__((ext_vector_type(8))) _Float16 f16x8;
typedef __attribute__((ext_vector_type(4))) float f32x4;

#if __has_builtin(__builtin_amdgcn_exp2f)
#define EXP2F(x) __builtin_amdgcn_exp2f(x)
#else
#define EXP2F(x) exp2f(x)
#endif
#if __has_builtin(__builtin_amdgcn_rcpf)
#define RCPF(x) __builtin_amdgcn_rcpf(x)
#else
#define RCPF(x) (1.0f / (x))
#endif
#define L2E 1.44269504088896340736f

__device__ __forceinline__ f16x2 bc2(unsigned u) { return __builtin_bit_cast(f16x2, u); }
__device__ __forceinline__ unsigned bcu(f16x2 v) { return __builtin_bit_cast(unsigned, v); }
__device__ __forceinline__ unsigned pk(float a, float b) {
    f16x2 t = {(f16)a, (f16)b};
    return __builtin_bit_cast(unsigned, t);
}

// combine 3 units: gate args arrive PRE-SCALED from the MFMA
// (i,f,o cols x(-L2E), j col x(-2L2E), forget bias+1 folded into bias row).
__device__ __forceinline__ void combine3(const f32x4* acc, float* cr, float* hr) {
    #pragma unroll
    for (int mg = 0; mg < 3; ++mg) {
        const f32x4 z = acc[mg];
        const float E0 = EXP2F(z[0]);                       // e^-zi
        const float E1 = EXP2F(z[1]);                       // e^-2zj
        const float R  = RCPF((1.0f + E0) * (1.0f + E1));
        const float ij = (1.0f - E1) * R;                   // sig(zi)*tanh(zj)
        const float E2 = EXP2F(z[2]);                       // e^-(zf+1)
        const float E3 = EXP2F(z[3]);                       // e^-zo
        const float R2 = RCPF((1.0f + E2) * (1.0f + E3));
        const float fg = (1.0f + E3) * R2;                  // sig(zf+1)
        const float og = (1.0f + E2) * R2;                  // sig(zo)
        cr[mg] = fg * cr[mg] + ij;
        const float u  = EXP2F(-2.0f * L2E * cr[mg]);
        const float th = (1.0f - u) * RCPF(1.0f + u);       // tanh(c)
        hr[mg] = og * th;
    }
}

__global__ __launch_bounds__(512, 4) void cnn_lstm_kernel(
    const int* __restrict__ inp, const float* __restrict__ emb,
    const float* __restrict__ k2, const float* __restrict__ k3,
    const float* __restrict__ k4,
    const float* __restrict__ wfw, const float* __restrict__ bfw,
    const float* __restrict__ wbw, const float* __restrict__ bbw,
    float* __restrict__ out)
{
    // ctab[v]: 4 age-slices x 12 conv feats (fp16) at 12-half offsets.
    __shared__ __align__(16) f16 ctab[(VOCAB + 1) * CROWH];   // 30.8 KB
    // X rows: 16 seqs x [x(12)|h(10)|bias|pad..] ; pad (halves 23..31) = 0.
    __shared__ __align__(16) f16 xbuf[WAVES][16][XROW];       // 8.2 KB

    const int tid  = threadIdx.x;
    const int lane = tid & 63;
    const int w    = tid >> 6;      // 0..7
    const int g    = lane >> 4;     // k-group / quad index / gather slot
    const int c16  = lane & 15;     // seq within wave / phys gate row (A side)

    // ---- build ctab: thread -> (vocab v = tid/2, two dlt slices) -----------
    {
        const int v  = tid >> 1;
        const int db = (tid & 1) * 2;
        float er[16];
        const float4* ep = (const float4*)(emb + v * 16);
        float4 e0 = ep[0], e1 = ep[1], e2 = ep[2], e3 = ep[3];
        er[0]=e0.x; er[1]=e0.y; er[2]=e0.z; er[3]=e0.w;
        er[4]=e1.x; er[5]=e1.y; er[6]=e1.z; er[7]=e1.w;
        er[8]=e2.x; er[9]=e2.y; er[10]=e2.z; er[11]=e2.w;
        er[12]=e3.x; er[13]=e3.y; er[14]=e3.z; er[15]=e3.w;

        #pragma unroll
        for (int dd = 0; dd < 2; ++dd) {
            const int dlt = db + dd;
            float o[12];
            #pragma unroll
            for (int f = 0; f < 12; ++f) o[f] = 0.0f;
            const int tap2 = 1 - dlt, tap3 = 2 - dlt, tap4 = 3 - dlt;
            if (tap2 >= 0) {
                #pragma unroll
                for (int e = 0; e < 16; ++e) {
                    const float x = er[e];
                    #pragma unroll
                    for (int f = 0; f < 3; ++f) o[f] += x * k2[(tap2 * 16 + e) * 3 + f];
                }
            }
            if (tap3 >= 0) {
                #pragma unroll
                for (int e = 0; e < 16; ++e) {
                    const float x = er[e];
                    #pragma unroll
                    for (int f = 0; f < 4; ++f) o[3 + f] += x * k3[(tap3 * 16 + e) * 4 + f];
                }
            }
            {
                #pragma unroll
                for (int e = 0; e < 16; ++e) {
                    const float x = er[e];
                    #pragma unroll
                    for (int f = 0; f < 5; ++f) o[7 + f] += x * k4[(tap4 * 16 + e) * 5 + f];
                }
            }
            uint2* dst = (uint2*)&ctab[v * CROWH + 12 * dlt];
            dst[0] = make_uint2(pk(o[0], o[1]), pk(o[2], o[3]));
            dst[1] = make_uint2(pk(o[4], o[5]), pk(o[6], o[7]));
            dst[2] = make_uint2(pk(o[8], o[9]), pk(o[10], o[11]));
        }
    }
    if (tid < 12) ((uint2*)&ctab[SENT * CROWH])[tid] = make_uint2(0u, 0u);

    // init h/bias/pad region (halves 12..31) of own wave's 16 rows
    if (g == 0) {
        uint2* xr = (uint2*)&xbuf[w][c16][12];
        xr[0] = make_uint2(0u, 0u);             // h0..h3
        xr[1] = make_uint2(0u, 0u);             // h4..h7
        xr[2] = make_uint2(0u, pk(1.0f, 0.0f)); // h8,h9 | bias,pad
        xr[3] = make_uint2(0u, 0u);             // K-pad 24..27
        xr[4] = make_uint2(0u, 0u);             // K-pad 28..31
    }
    __syncthreads();

    // ---- per-(seq, dir): wave = 16 seqs, 4 lanes/seq ------------------------
    const int dir = blockIdx.x >> 9;              // 1024 blocks: 0..511 fw
    const bool fw = (dir == 0);
    const int nbase = (blockIdx.x & 511) * 128 + w * 16;
    const int n = nbase + c16;
    const int* inp_n = inp + n * SC;
    const float* Wm = fw ? wfw : wbw;
    const float* Bv = fw ? bfw : bbw;

    // A-frags, loaded once, PRE-SCALED: phys gate row c16 = part r=c16&3 of
    // quad qg=c16>>2; tile mg holds quads Lq = {2qg, 2qg+1, 8+qg}.
    // k rows: 0..11 x, 12..21 h, 22 bias(+1 for f), 23..31 zero.
    f16x8 afr[3];
    {
        const int qg = c16 >> 2, r = c16 & 3;
        const float sc = (r == 1) ? (-2.0f * L2E) : (-L2E);
        #pragma unroll
        for (int mg = 0; mg < 3; ++mg) {
            const int Lq = (mg == 0) ? 2 * qg : (mg == 1) ? (2 * qg + 1) : (8 + qg);
            const bool valid = (Lq < HDIM);
            const int lcol = r * HDIM + Lq;
            #pragma unroll
            for (int i = 0; i < 8; ++i) {
                const int kk = 8 * g + i;
                float val = 0.0f;
                if (valid) {
                    if (kk < 22)       val = Wm[kk * 40 + lcol];
                    else if (kk == 22) val = Bv[lcol] + ((r == 2) ? 1.0f : 0.0f);
                    val *= sc;
                }
                afr[mg][i] = (f16)val;
            }
        }
    }

    auto chload = [&](int q) -> int {
        return ((unsigned)q < (unsigned)SC) ? inp_n[q] : SENT;
    };

    // lane g commits x(T) for T = g, g+4, g+8, ...; pp = char pos of age-0.
    int pp = fw ? g : (SC - 1 - g);
    int a0 = chload(pp), a1 = chload(pp - 1), a2 = chload(pp - 2), a3 = chload(pp - 3);

    // prologue: g==0 lanes gather + commit x(0) for their seq
    if (g == 0) {
        const uint2* s0 = (const uint2*)&ctab[a0 * CROWH];
        const uint2* s1 = (const uint2*)&ctab[a1 * CROWH + 12];
        const uint2* s2 = (const uint2*)&ctab[a2 * CROWH + 24];
        const uint2* s3 = (const uint2*)&ctab[a3 * CROWH + 36];
        uint2 q0 = s0[0], q1 = s0[1], q2 = s0[2];
        uint2 r0 = s1[0], r1 = s1[1], r2 = s1[2];
        uint2 u0 = s2[0], u1 = s2[1], u2 = s2[2];
        uint2 v0 = s3[0], v1 = s3[1], v2 = s3[2];
        f16x2 m0 = bc2(q0.x) + bc2(r0.x) + bc2(u0.x) + bc2(v0.x);
        f16x2 m1 = bc2(q0.y) + bc2(r0.y) + bc2(u0.y) + bc2(v0.y);
        f16x2 m2 = bc2(q1.x) + bc2(r1.x) + bc2(u1.x) + bc2(v1.x);
        f16x2 m3 = bc2(q1.y) + bc2(r1.y) + bc2(u1.y) + bc2(v1.y);
        f16x2 m4 = bc2(q2.x) + bc2(r2.x) + bc2(u2.x) + bc2(v2.x);
        f16x2 m5 = bc2(q2.y) + bc2(r2.y) + bc2(u2.y) + bc2(v2.y);
        uint2* dst = (uint2*)&xbuf[w][c16][0];
        dst[0] = make_uint2(bcu(m0), bcu(m1));
        dst[1] = make_uint2(bcu(m2), bcu(m3));
        dst[2] = make_uint2(bcu(m4), bcu(m5));
        pp += fw ? 4 : -4;
        a0 = chload(pp); a1 = chload(pp - 1); a2 = chload(pp - 2); a3 = chload(pp - 3);
    }

    float creg[3] = {0.f, 0.f, 0.f};
    float hreg[3] = {0.f, 0.f, 0.f};

    #pragma unroll 1
    for (int t = 0; t < SC; ++t) {
        // 1. B-frag of x(t)+h(t-1) (committed by prior program-order writes)
        f16x8 bf = *(const f16x8*)&xbuf[w][c16][8 * g];

        // 2. committer lanes: issue age 0,1 reads for x(t+1)
        const bool act = (t < SC - 1) && (g == ((t + 1) & 3));
        uint2 pA0, pA1, pA2, pB0, pB1, pB2;
        if (act) {
            const uint2* s0 = (const uint2*)&ctab[a0 * CROWH];
            pA0 = s0[0]; pA1 = s0[1]; pA2 = s0[2];
            const uint2* s1 = (const uint2*)&ctab[a1 * CROWH + 12];
            pB0 = s1[0]; pB1 = s1[1]; pB2 = s1[2];
        }
        __builtin_amdgcn_sched_barrier(0);

        // 3. MFMAs: Z rows (gates) x cols (seqs), K=32
        f32x4 acc[3];
        const f32x4 zero4 = {0.0f, 0.0f, 0.0f, 0.0f};
        acc[0] = __builtin_amdgcn_mfma_f32_16x16x32_f16(afr[0], bf, zero4, 0, 0, 0);
        acc[1] = __builtin_amdgcn_mfma_f32_16x16x32_f16(afr[1], bf, zero4, 0, 0, 0);
        acc[2] = __builtin_amdgcn_mfma_f32_16x16x32_f16(afr[2], bf, zero4, 0, 0, 0);
        __builtin_amdgcn_sched_barrier(0);

        // 4. committer: fold ages 0,1; issue age 2,3 reads (reuse regs)
        unsigned xg0, xg1, xg2, xg3, xg4, xg5;
        if (act) {
            xg0 = bcu(bc2(pA0.x) + bc2(pB0.x));
            xg1 = bcu(bc2(pA0.y) + bc2(pB0.y));
            xg2 = bcu(bc2(pA1.x) + bc2(pB1.x));
            xg3 = bcu(bc2(pA1.y) + bc2(pB1.y));
            xg4 = bcu(bc2(pA2.x) + bc2(pB2.x));
            xg5 = bcu(bc2(pA2.y) + bc2(pB2.y));
            const uint2* s2 = (const uint2*)&ctab[a2 * CROWH + 24];
            pA0 = s2[0]; pA1 = s2[1]; pA2 = s2[2];
            const uint2* s3 = (const uint2*)&ctab[a3 * CROWH + 36];
            pB0 = s3[0]; pB1 = s3[1]; pB2 = s3[2];
        }
        __builtin_amdgcn_sched_barrier(0);

        // 5. combine (trans-heavy, hides the age-2,3 read latency) + h-writes
        combine3(acc, creg, hreg);
        {
            f16* xr = &xbuf[w][c16][0];
            *(unsigned*)(xr + 12 + 2 * g) = pk(hreg[0], hreg[1]);
            if (g < 2) xr[20 + g] = (f16)hreg[2];
        }

        // 6. committer: fold ages 2,3; commit x(t+1); advance chars (T+4)
        if (act) {
            xg0 = bcu(bc2(xg0) + bc2(pA0.x) + bc2(pB0.x));
            xg1 = bcu(bc2(xg1) + bc2(pA0.y) + bc2(pB0.y));
            xg2 = bcu(bc2(xg2) + bc2(pA1.x) + bc2(pB1.x));
            xg3 = bcu(bc2(xg3) + bc2(pA1.y) + bc2(pB1.y));
            xg4 = bcu(bc2(xg4) + bc2(pA2.x) + bc2(pB2.x));
            xg5 = bcu(bc2(xg5) + bc2(pA2.y) + bc2(pB2.y));
            uint2* dst = (uint2*)&xbuf[w][c16][0];
            dst[0] = make_uint2(xg0, xg1);
            dst[1] = make_uint2(xg2, xg3);
            dst[2] = make_uint2(xg4, xg5);
            pp += fw ? 4 : -4;
            a0 = chload(pp); a1 = chload(pp - 1); a2 = chload(pp - 2); a3 = chload(pp - 3);
        }
        __builtin_amdgcn_sched_barrier(0);
    }

    // ---- output: lane owns h-units {2g, 2g+1, 8+g} of seq c16 --------------
    {
        float2 hv;
        hv.x = hreg[0];
        hv.y = hreg[1];
        *(float2*)&out[n * (2 * HDIM) + dir * HDIM + 2 * g] = hv;
        if (g < 2) out[n * (2 * HDIM) + dir * HDIM + 8 + g] = hreg[2];
    }
}

extern "C" void kernel_launch(void* const* d_in, const int* in_sizes, int n_in,
                              void* d_out, int out_size, void* d_ws, size_t ws_size,
                              hipStream_t stream) {
    const int*   inp = (const int*)d_in[0];
    const float* emb = (const float*)d_in[1];
    const float* k2  = (const float*)d_in[2];
    const float* k3  = (const float*)d_in[3];
    const float* k4  = (const float*)d_in[4];
    const float* wfw = (const float*)d_in[5];
    const float* bfw = (const float*)d_in[6];
    const float* wbw = (const float*)d_in[7];
    const float* bbw = (const float*)d_in[8];
    float* out = (float*)d_out;

    // 1024 blocks x 512 threads = 8192 waves, 16 seqs/wave.
    // Exactly 4 blocks/CU x 256 CUs -> 32 waves/CU, zero tail rounds.
    cnn_lstm_kernel<<<dim3(1024), dim3(512), 0, stream>>>(
        inp, emb, k2, k3, k4, wfw, bfw, wbw, bbw, out);
}